// Round 3
// baseline (430.727 us; speedup 1.0000x reference)
//
#include <hip/hip_runtime.h>
#include <hip/hip_bf16.h>

using bf16 = __hip_bfloat16;
typedef __attribute__((ext_vector_type(8))) short bf16x8;   // 8 bf16 in 4 VGPRs (MFMA A/B frag)
typedef __attribute__((ext_vector_type(4))) short short4v;  // 4 bf16 packed store
typedef __attribute__((ext_vector_type(4))) float f32x4;    // MFMA C/D frag

#define MFMA(a, b, c) __builtin_amdgcn_mfma_f32_16x16x32_bf16((a), (b), (c), 0, 0, 0)

// Problem constants
#define S_LEN 4096
#define D_MODEL 256
#define NH 4
#define HD 64
#define NTOK 8192  // B*S

static __device__ __forceinline__ short f2bf(float f) {
  bf16 h = __float2bfloat16(f);
  return *reinterpret_cast<short*>(&h);
}
static __device__ __forceinline__ float to_f(bf16 v) { return __bfloat162float(v); }
static __device__ __forceinline__ float to_f(float v) { return v; }

// 8-element bf16 MFMA fragment load; fp32 source converts inline.
static __device__ __forceinline__ bf16x8 load8(const bf16* p) {
  return *(const bf16x8*)p;
}
static __device__ __forceinline__ bf16x8 load8(const float* p) {
  const float4* q = (const float4*)p;
  float4 a = q[0], b = q[1];
  bf16x8 r;
  r[0] = f2bf(a.x); r[1] = f2bf(a.y); r[2] = f2bf(a.z); r[3] = f2bf(a.w);
  r[4] = f2bf(b.x); r[5] = f2bf(b.y); r[6] = f2bf(b.z); r[7] = f2bf(b.w);
  return r;
}
static __device__ __forceinline__ void store1(bf16* p, float v) { *p = __float2bfloat16(v); }
static __device__ __forceinline__ void store1(float* p, float v) { *p = v; }

// ---------------------------------------------------------------------------
// Kernel 0: dtype detector. bf16 N(0,1) data: even-indexed uint16s have
// exponent-field (bits 14:7) in [100,140] ~always. fp32 data: even shorts are
// low mantissa halves -> uniform -> ~16% in range. Threshold at 50%.
// flag = 1 -> bf16 I/O, flag = 0 -> fp32 I/O.
// ---------------------------------------------------------------------------
__global__ void detect_dtype(const unsigned short* __restrict__ q, int* __restrict__ flag) {
  __shared__ int cnt_s;
  if (threadIdx.x == 0) cnt_s = 0;
  __syncthreads();
  int c = 0;
  for (int i = threadIdx.x; i < 8192; i += 256) {
    const int e = (q[2 * i] >> 7) & 0xFF;
    c += (e >= 100 && e <= 140) ? 1 : 0;
  }
  atomicAdd(&cnt_s, c);
  __syncthreads();
  if (threadIdx.x == 0) *flag = (cnt_s > 4096) ? 1 : 0;
}

// ---------------------------------------------------------------------------
// Kernel 1: QKV projections (templated on input scalar type, gated by flag).
//   z=0: Q = (x@wq.T + bq) * 0.125  -> qg[b][h][s][hd]   (scale folded in)
//   z=1: K = (x@wk.T + bk)          -> kg[b][h][s][hd]
//   z=2: V = (x@wv.T + bv)          -> vt[b][h][hd][s]   (swapped MFMA roles)
// MFMA 16x16x32 layouts (HW-verified): A[m=lane&15][k=quad*8+j],
// B[k=quad*8+j][n=lane&15], C/D row=quad*4+reg col=lane&15.
// ---------------------------------------------------------------------------
template <typename T>
__global__ __launch_bounds__(256) void qkv_proj(
    const int* __restrict__ flag, int want,
    const T* __restrict__ q_in, const T* __restrict__ k_in, const T* __restrict__ v_in,
    const T* __restrict__ wq, const T* __restrict__ bq_,
    const T* __restrict__ wk, const T* __restrict__ bk_,
    const T* __restrict__ wv, const T* __restrict__ bv_,
    bf16* __restrict__ qg, bf16* __restrict__ kg, bf16* __restrict__ vtg) {
  if (*flag != want) return;
  const int wave = threadIdx.x >> 6;
  const int lane = threadIdx.x & 63;
  const int quad = lane >> 4;
  const int l16  = lane & 15;
  const int z = blockIdx.z;

  const T* X  = (z == 0) ? q_in : (z == 1) ? k_in : v_in;
  const T* W  = (z == 0) ? wq   : (z == 1) ? wk   : wv;
  const T* Bp = (z == 0) ? bq_  : (z == 1) ? bk_  : bv_;

  f32x4 acc[4] = {};

  if (z < 2) {
    // M = tokens, N = output channels
    const int m0 = blockIdx.x * 64 + wave * 16;
    const int n0 = blockIdx.y * 64;
    for (int kk = 0; kk < D_MODEL; kk += 32) {
      bf16x8 a = load8(X + (size_t)(m0 + l16) * D_MODEL + kk + quad * 8);
#pragma unroll
      for (int nt = 0; nt < 4; ++nt) {
        bf16x8 b = load8(W + (size_t)(n0 + nt * 16 + l16) * D_MODEL + kk + quad * 8);
        acc[nt] = MFMA(a, b, acc[nt]);
      }
    }
    bf16* dst = (z == 0) ? qg : kg;
    const float scale = (z == 0) ? 0.125f : 1.0f;  // 1/sqrt(HD) folded into Q
#pragma unroll
    for (int nt = 0; nt < 4; ++nt) {
      const int o = n0 + nt * 16 + l16;
      const float bias = to_f(Bp[o]);
      const int h = o >> 6, hd = o & 63;
#pragma unroll
      for (int r = 0; r < 4; ++r) {
        const int t = m0 + quad * 4 + r;
        const int b_ = t >> 12, s = t & 4095;
        const float v = (acc[nt][r] + bias) * scale;
        dst[((size_t)((b_ * NH + h) * S_LEN + s)) * HD + hd] = __float2bfloat16(v);
      }
    }
  } else {
    // V transposed: M = output channels, N = tokens
    const int o0 = blockIdx.y * 64 + wave * 16;
    const int t0 = blockIdx.x * 64;
    for (int kk = 0; kk < D_MODEL; kk += 32) {
      bf16x8 a = load8(W + (size_t)(o0 + l16) * D_MODEL + kk + quad * 8);
#pragma unroll
      for (int nt = 0; nt < 4; ++nt) {
        bf16x8 b = load8(X + (size_t)(t0 + nt * 16 + l16) * D_MODEL + kk + quad * 8);
        acc[nt] = MFMA(a, b, acc[nt]);
      }
    }
    const int h = blockIdx.y;  // o0 block aligned to head boundary (64)
#pragma unroll
    for (int r = 0; r < 4; ++r) {
      const int o = o0 + quad * 4 + r;
      const float bias = to_f(Bp[o]);
      const int hd = o & 63;
#pragma unroll
      for (int nt = 0; nt < 4; ++nt) {
        const int t = t0 + nt * 16 + l16;
        const int b_ = t >> 12, s = t & 4095;
        vtg[((size_t)((b_ * NH + h) * HD + hd)) * S_LEN + s] = __float2bfloat16(acc[nt][r] + bias);
      }
    }
  }
}

// ---------------------------------------------------------------------------
// Kernel 2: flash attention, transposed-score formulation (shared by both
// modes; pointers selected by flag). S^T = K·Q^T, softmax on quad/reg axis,
// P via wave-private LDS round trip, O^T = V^T·P^T.
// ---------------------------------------------------------------------------
__global__ __launch_bounds__(256) void attn_fwd(
    const int* __restrict__ flag,
    const bf16* qgA, const bf16* kgA, const bf16* vtA, bf16* attnA,
    const bf16* qgB, const bf16* kgB, const bf16* vtB, bf16* attnB) {
  const int f = *flag;
  const bf16* qg  = f ? qgA : qgB;
  const bf16* kg  = f ? kgA : kgB;
  const bf16* vtg = f ? vtA : vtB;
  bf16* attn      = f ? attnA : attnB;

  const int wave = threadIdx.x >> 6;
  const int lane = threadIdx.x & 63;
  const int quad = lane >> 4;
  const int l16  = lane & 15;
  const int q0 = blockIdx.x * 64;
  const int bh = blockIdx.y;

  const bf16* qb = qg  + (size_t)bh * S_LEN * HD;
  const bf16* kb = kg  + (size_t)bh * S_LEN * HD;
  const bf16* vb = vtg + (size_t)bh * HD * S_LEN;

  __shared__ short p_lds[4 * 16 * 64];  // per-wave 16(q) x 64(j) bf16 tile

  const int qrow = q0 + wave * 16 + l16;
  bf16x8 qf0 = *(const bf16x8*)(qb + (size_t)qrow * HD + quad * 8);
  bf16x8 qf1 = *(const bf16x8*)(qb + (size_t)qrow * HD + 32 + quad * 8);

  float m_i = -1.0e30f, l_i = 0.f;
  f32x4 oT[4] = {};
  const int pb = wave * 1024 + l16 * 64;

  for (int j0 = 0; j0 < S_LEN; j0 += 64) {
    // S^T tiles: rows j = j0 + ct*16 + quad*4 + reg, col i = l16
    f32x4 st[4] = {};
#pragma unroll
    for (int ct = 0; ct < 4; ++ct) {
      const bf16* krow = kb + (size_t)(j0 + ct * 16 + l16) * HD;
      bf16x8 kf0 = *(const bf16x8*)(krow + quad * 8);
      bf16x8 kf1 = *(const bf16x8*)(krow + 32 + quad * 8);
      st[ct] = MFMA(kf0, qf0, st[ct]);
      st[ct] = MFMA(kf1, qf1, st[ct]);
    }
    // online softmax (per query row i = l16; quads combined via shfl)
    float mx = st[0][0];
#pragma unroll
    for (int ct = 0; ct < 4; ++ct)
#pragma unroll
      for (int r = 0; r < 4; ++r) mx = fmaxf(mx, st[ct][r]);
    mx = fmaxf(mx, __shfl_xor(mx, 16));
    mx = fmaxf(mx, __shfl_xor(mx, 32));
    const float m_new = fmaxf(m_i, mx);
    const float alpha = __expf(m_i - m_new);
    float rs = 0.f;
#pragma unroll
    for (int ct = 0; ct < 4; ++ct)
#pragma unroll
      for (int r = 0; r < 4; ++r) {
        const float p = __expf(st[ct][r] - m_new);
        st[ct][r] = p;
        rs += p;
      }
    rs += __shfl_xor(rs, 16);
    rs += __shfl_xor(rs, 32);
    l_i = l_i * alpha + rs;
    m_i = m_new;
#pragma unroll
    for (int t = 0; t < 4; ++t)
#pragma unroll
      for (int r = 0; r < 4; ++r) oT[t][r] *= alpha;

    // P^T (C-layout) -> LDS as P[i][j], j contiguous (wave-private region)
#pragma unroll
    for (int ct = 0; ct < 4; ++ct) {
      short4v pk;
      pk[0] = f2bf(st[ct][0]);
      pk[1] = f2bf(st[ct][1]);
      pk[2] = f2bf(st[ct][2]);
      pk[3] = f2bf(st[ct][3]);
      *(short4v*)&p_lds[pb + ct * 16 + quad * 4] = pk;
    }
    __syncthreads();
    bf16x8 bp0 = *(const bf16x8*)&p_lds[pb + quad * 8];
    bf16x8 bp1 = *(const bf16x8*)&p_lds[pb + 32 + quad * 8];

    // O^T[d][i] += sum_j V^T[d][j] * P^T[j][i]
#pragma unroll
    for (int t = 0; t < 4; ++t) {
      const bf16* vrow = vb + (size_t)(t * 16 + l16) * S_LEN + j0;
      bf16x8 av0 = *(const bf16x8*)(vrow + quad * 8);
      bf16x8 av1 = *(const bf16x8*)(vrow + 32 + quad * 8);
      oT[t] = MFMA(av0, bp0, oT[t]);
      oT[t] = MFMA(av1, bp1, oT[t]);
    }
  }

  const float inv = 1.0f / l_i;
  const int b_ = bh >> 2, h = bh & 3;
  bf16* ob = attn + ((size_t)(b_ * S_LEN + q0 + wave * 16 + l16)) * D_MODEL + h * HD;
#pragma unroll
  for (int t = 0; t < 4; ++t) {
    short4v pk;
#pragma unroll
    for (int r = 0; r < 4; ++r) pk[r] = f2bf(oT[t][r] * inv);
    *(short4v*)(ob + t * 16 + quad * 4) = pk;
  }
}

// ---------------------------------------------------------------------------
// Kernel 3: out-projection (attn @ wo.T + bo) + LayerNorm, per 16 tokens.
// Templated on weight/output scalar type, gated by flag. bf16 mode operates
// in place on d_out (aliasing: no __restrict__ on attn/out).
// ---------------------------------------------------------------------------
template <typename T>
__global__ __launch_bounds__(256) void out_ln(
    const int* __restrict__ flag, int want,
    const bf16* attn, const T* __restrict__ wo,
    const T* __restrict__ bo_, const T* __restrict__ gamma,
    const T* __restrict__ beta, T* out) {
  if (*flag != want) return;
  const int tid = threadIdx.x;
  const int wave = tid >> 6;
  const int lane = tid & 63;
  const int quad = lane >> 4;
  const int l16  = lane & 15;
  const int t0 = blockIdx.x * 16;

  __shared__ float ybuf[16 * 256];
  __shared__ float mu_s[16], rs_s[16];

  f32x4 acc[4] = {};
  const int n0 = wave * 64;
  for (int kk = 0; kk < D_MODEL; kk += 32) {
    bf16x8 a = *(const bf16x8*)(attn + (size_t)(t0 + l16) * D_MODEL + kk + quad * 8);
#pragma unroll
    for (int nt = 0; nt < 4; ++nt) {
      bf16x8 b = load8(wo + (size_t)(n0 + nt * 16 + l16) * D_MODEL + kk + quad * 8);
      acc[nt] = MFMA(a, b, acc[nt]);
    }
  }
#pragma unroll
  for (int nt = 0; nt < 4; ++nt) {
    const int o = n0 + nt * 16 + l16;
    const float bias = to_f(bo_[o]);
#pragma unroll
    for (int r = 0; r < 4; ++r) ybuf[(quad * 4 + r) * 256 + o] = acc[nt][r] + bias;
  }
  __syncthreads();

  // wave w reduces rows [4w, 4w+4)
#pragma unroll
  for (int rr = 0; rr < 4; ++rr) {
    const int row = wave * 4 + rr;
    float s1 = 0.f, s2 = 0.f;
#pragma unroll
    for (int c = 0; c < 4; ++c) {
      const float v = ybuf[row * 256 + c * 64 + lane];
      s1 += v;
      s2 += v * v;
    }
#pragma unroll
    for (int m = 32; m >= 1; m >>= 1) {
      s1 += __shfl_xor(s1, m);
      s2 += __shfl_xor(s2, m);
    }
    if (lane == 0) {
      const float mu = s1 * (1.f / 256.f);
      const float var = s2 * (1.f / 256.f) - mu * mu;
      mu_s[row] = mu;
      rs_s[row] = rsqrtf(var + 1e-5f);
    }
  }
  __syncthreads();

  const float g  = to_f(gamma[tid]);
  const float be = to_f(beta[tid]);
#pragma unroll 4
  for (int row = 0; row < 16; ++row) {
    const float v = ybuf[row * 256 + tid];
    const float o = (v - mu_s[row]) * rs_s[row] * g + be;
    store1(&out[(size_t)(t0 + row) * D_MODEL + tid], o);
  }
}

// ---------------------------------------------------------------------------
extern "C" void kernel_launch(void* const* d_in, const int* in_sizes, int n_in,
                              void* d_out, int out_size, void* d_ws, size_t ws_size,
                              hipStream_t stream) {
  int* flag = (int*)d_ws;
  bf16* wsdata = (bf16*)((char*)d_ws + 256);
  const size_t SEG = (size_t)NTOK * D_MODEL;  // 2,097,152 elements = 4 MB bf16

  // Mode A (bf16 I/O): qg/kg/vt in ws (12 MB); attn scratch = d_out (bf16, in-place LN)
  bf16* qgA = wsdata;
  bf16* kgA = wsdata + SEG;
  bf16* vtA = wsdata + 2 * SEG;
  bf16* attnA = (bf16*)d_out;
  // Mode B (fp32 I/O): qg/kg staged in d_out (8 MB fp32 = 2 SEG bf16);
  // vt + attn in ws (8 MB). out_ln overwrites d_out with fp32 (qg/kg dead then).
  bf16* qgB = (bf16*)d_out;
  bf16* kgB = qgB + SEG;
  bf16* vtB = wsdata;
  bf16* attnB = wsdata + SEG;

  detect_dtype<<<1, 256, 0, stream>>>((const unsigned short*)d_in[0], flag);

  qkv_proj<bf16><<<dim3(128, 4, 3), 256, 0, stream>>>(
      flag, 1, (const bf16*)d_in[0], (const bf16*)d_in[1], (const bf16*)d_in[2],
      (const bf16*)d_in[3], (const bf16*)d_in[4], (const bf16*)d_in[5], (const bf16*)d_in[6],
      (const bf16*)d_in[7], (const bf16*)d_in[8], qgA, kgA, vtA);
  qkv_proj<float><<<dim3(128, 4, 3), 256, 0, stream>>>(
      flag, 0, (const float*)d_in[0], (const float*)d_in[1], (const float*)d_in[2],
      (const float*)d_in[3], (const float*)d_in[4], (const float*)d_in[5], (const float*)d_in[6],
      (const float*)d_in[7], (const float*)d_in[8], qgB, kgB, vtB);

  attn_fwd<<<dim3(64, 8), 256, 0, stream>>>(flag, qgA, kgA, vtA, attnA,
                                            qgB, kgB, vtB, attnB);

  out_ln<bf16><<<dim3(512), 256, 0, stream>>>(
      flag, 1, attnA, (const bf16*)d_in[9], (const bf16*)d_in[10],
      (const bf16*)d_in[11], (const bf16*)d_in[12], (bf16*)d_out);
  out_ln<float><<<dim3(512), 256, 0, stream>>>(
      flag, 0, attnB, (const float*)d_in[9], (const float*)d_in[10],
      (const float*)d_in[11], (const float*)d_in[12], (float*)d_out);
}

// Round 8
// 395.452 us; speedup vs baseline: 1.0892x; 1.0892x over previous
//
#include <hip/hip_runtime.h>
#include <hip/hip_bf16.h>

using bf16 = __hip_bfloat16;
typedef __attribute__((ext_vector_type(8))) short bf16x8;   // 8 bf16 in 4 VGPRs (MFMA A/B frag)
typedef __attribute__((ext_vector_type(4))) short short4v;  // 4 bf16 packed store
typedef __attribute__((ext_vector_type(4))) float f32x4;    // MFMA C/D frag

#define MFMA(a, b, c) __builtin_amdgcn_mfma_f32_16x16x32_bf16((a), (b), (c), 0, 0, 0)

// Problem constants
#define S_LEN 4096
#define D_MODEL 256
#define NH 4
#define HD 64
#define NTOK 8192   // B*S
#define PROW 72     // P-tile LDS row stride in shorts (144 B = 9*16 B): keeps
                    // 16B alignment, spreads accesses across all 32 banks
                    // (stride 64 = 128 B hits only banks 0-15 -> 16-way, R3)

// DTYPE RESOLUTION (R3-R7 evidence): inputs and output are FP32, per the
// reference. R3's dual-dtype kernel passed via its fp32 path (flag=0); every
// bf16-cast variant (R4-R7) NaN'd on garbage Q/K/V. Do NOT cast d_in to bf16.

static __device__ __forceinline__ short f2bf(float f) {
  bf16 h = __float2bfloat16(f);
  return *reinterpret_cast<short*>(&h);
}

// 8 consecutive fp32 -> bf16x8 MFMA fragment (two float4 loads + inline cvt).
static __device__ __forceinline__ bf16x8 cvt8(const float* p) {
  const float4 a = ((const float4*)p)[0];
  const float4 b = ((const float4*)p)[1];
  bf16x8 r;
  r[0] = f2bf(a.x); r[1] = f2bf(a.y); r[2] = f2bf(a.z); r[3] = f2bf(a.w);
  r[4] = f2bf(b.x); r[5] = f2bf(b.y); r[6] = f2bf(b.z); r[7] = f2bf(b.w);
  return r;
}

// ---------------------------------------------------------------------------
// Kernel 1: QKV projections. fp32 inputs/weights, bf16 outputs (MFMA staging).
//   z=0: Q = (x@wq.T + bq) * 0.125  -> qg[b][h][s][hd]   (scale folded in)
//   z=1: K = (x@wk.T + bk)          -> kg[b][h][s][hd]
//   z=2: V = (x@wv.T + bv)          -> vt[b][h][hd][s]   (swapped MFMA roles)
// MFMA 16x16x32 layouts (HW-verified): A[m=lane&15][k=quad*8+j],
// B[k=quad*8+j][n=lane&15], C/D row=quad*4+reg col=lane&15.
// ---------------------------------------------------------------------------
__global__ __launch_bounds__(256) void qkv_proj(
    const float* __restrict__ q_in, const float* __restrict__ k_in, const float* __restrict__ v_in,
    const float* __restrict__ wq, const float* __restrict__ bq_,
    const float* __restrict__ wk, const float* __restrict__ bk_,
    const float* __restrict__ wv, const float* __restrict__ bv_,
    bf16* __restrict__ qg, bf16* __restrict__ kg, bf16* __restrict__ vtg) {
  const int wave = threadIdx.x >> 6;
  const int lane = threadIdx.x & 63;
  const int quad = lane >> 4;
  const int l16  = lane & 15;
  const int z = blockIdx.z;

  const float* X  = (z == 0) ? q_in : (z == 1) ? k_in : v_in;
  const float* W  = (z == 0) ? wq   : (z == 1) ? wk   : wv;
  const float* Bp = (z == 0) ? bq_  : (z == 1) ? bk_  : bv_;

  f32x4 acc[4] = {};

  if (z < 2) {
    // M = tokens, N = output channels
    const int m0 = blockIdx.x * 64 + wave * 16;
    const int n0 = blockIdx.y * 64;
    for (int kk = 0; kk < D_MODEL; kk += 32) {
      bf16x8 a = cvt8(X + (size_t)(m0 + l16) * D_MODEL + kk + quad * 8);
#pragma unroll
      for (int nt = 0; nt < 4; ++nt) {
        bf16x8 b = cvt8(W + (size_t)(n0 + nt * 16 + l16) * D_MODEL + kk + quad * 8);
        acc[nt] = MFMA(a, b, acc[nt]);
      }
    }
    bf16* dst = (z == 0) ? qg : kg;
    const float scale = (z == 0) ? 0.125f : 1.0f;  // 1/sqrt(HD) folded into Q
#pragma unroll
    for (int nt = 0; nt < 4; ++nt) {
      const int o = n0 + nt * 16 + l16;
      const float bias = Bp[o];
      const int h = o >> 6, hd = o & 63;
#pragma unroll
      for (int r = 0; r < 4; ++r) {
        const int t = m0 + quad * 4 + r;
        const int b_ = t >> 12, s = t & 4095;
        const float v = (acc[nt][r] + bias) * scale;
        dst[((size_t)((b_ * NH + h) * S_LEN + s)) * HD + hd] = __float2bfloat16(v);
      }
    }
  } else {
    // V transposed: M = output channels, N = tokens
    const int o0 = blockIdx.y * 64 + wave * 16;
    const int t0 = blockIdx.x * 64;
    for (int kk = 0; kk < D_MODEL; kk += 32) {
      bf16x8 a = cvt8(W + (size_t)(o0 + l16) * D_MODEL + kk + quad * 8);
#pragma unroll
      for (int nt = 0; nt < 4; ++nt) {
        bf16x8 b = cvt8(X + (size_t)(t0 + nt * 16 + l16) * D_MODEL + kk + quad * 8);
        acc[nt] = MFMA(a, b, acc[nt]);
      }
    }
    const int h = blockIdx.y;  // o0 block aligned to head boundary (64)
#pragma unroll
    for (int r = 0; r < 4; ++r) {
      const int o = o0 + quad * 4 + r;
      const float bias = Bp[o];
      const int hd = o & 63;
#pragma unroll
      for (int nt = 0; nt < 4; ++nt) {
        const int t = t0 + nt * 16 + l16;
        const int b_ = t >> 12, s = t & 4095;
        vtg[((size_t)((b_ * NH + h) * HD + hd)) * S_LEN + s] = __float2bfloat16(acc[nt][r] + bias);
      }
    }
  }
}

// ---------------------------------------------------------------------------
// Kernel 2: flash attention, transposed-score formulation. All-bf16 internal.
//   R3-PROVEN structure (inline K/V loads, __syncthreads between P write and
//   P read, launch_bounds(256), no prefetch). ONE perf delta: P rows padded
//   to PROW=72 shorts (kills the measured 16-way bank conflicts, 3.46e7 cyc).
//   S^T = K·Q^T (softmax reduction on quad/reg axis, 2 shuffles for stats);
//   O^T = V^T·P^T accumulated in C-layout.
// ---------------------------------------------------------------------------
__global__ __launch_bounds__(256) void attn_fwd(
    const bf16* qg, const bf16* kg, const bf16* vtg, bf16* attn) {
  const int wave = threadIdx.x >> 6;
  const int lane = threadIdx.x & 63;
  const int quad = lane >> 4;
  const int l16  = lane & 15;
  const int q0 = blockIdx.x * 64;
  const int bh = blockIdx.y;

  const bf16* qb = qg  + (size_t)bh * S_LEN * HD;
  const bf16* kb = kg  + (size_t)bh * S_LEN * HD;
  const bf16* vb = vtg + (size_t)bh * HD * S_LEN;

  __shared__ short p_lds[4 * 16 * PROW];  // per-wave 16(q) x 64(j) bf16, padded rows

  const int qrow = q0 + wave * 16 + l16;
  bf16x8 qf0 = *(const bf16x8*)(qb + (size_t)qrow * HD + quad * 8);
  bf16x8 qf1 = *(const bf16x8*)(qb + (size_t)qrow * HD + 32 + quad * 8);

  float m_i = -1.0e30f, l_i = 0.f;
  f32x4 oT[4] = {};
  const int pb = wave * (16 * PROW) + l16 * PROW;

  for (int j0 = 0; j0 < S_LEN; j0 += 64) {
    // S^T tiles: rows j = j0 + ct*16 + quad*4 + reg, col i = l16
    f32x4 st[4] = {};
#pragma unroll
    for (int ct = 0; ct < 4; ++ct) {
      const bf16* krow = kb + (size_t)(j0 + ct * 16 + l16) * HD;
      bf16x8 kf0 = *(const bf16x8*)(krow + quad * 8);
      bf16x8 kf1 = *(const bf16x8*)(krow + 32 + quad * 8);
      st[ct] = MFMA(kf0, qf0, st[ct]);
      st[ct] = MFMA(kf1, qf1, st[ct]);
    }
    // online softmax (per query row i = l16; quads combined via 2 shuffles)
    float mx = st[0][0];
#pragma unroll
    for (int ct = 0; ct < 4; ++ct)
#pragma unroll
      for (int r = 0; r < 4; ++r) mx = fmaxf(mx, st[ct][r]);
    mx = fmaxf(mx, __shfl_xor(mx, 16));
    mx = fmaxf(mx, __shfl_xor(mx, 32));
    const float m_new = fmaxf(m_i, mx);
    const float alpha = __expf(m_i - m_new);
    float rs = 0.f;
#pragma unroll
    for (int ct = 0; ct < 4; ++ct)
#pragma unroll
      for (int r = 0; r < 4; ++r) {
        const float p = __expf(st[ct][r] - m_new);
        st[ct][r] = p;
        rs += p;
      }
    rs += __shfl_xor(rs, 16);
    rs += __shfl_xor(rs, 32);
    l_i = l_i * alpha + rs;
    m_i = m_new;
#pragma unroll
    for (int t = 0; t < 4; ++t)
#pragma unroll
      for (int r = 0; r < 4; ++r) oT[t][r] *= alpha;

    // P^T (C-layout) -> LDS as P[i][j] (padded rows), 4x packed short4 writes
#pragma unroll
    for (int ct = 0; ct < 4; ++ct) {
      short4v pk;
      pk[0] = f2bf(st[ct][0]);
      pk[1] = f2bf(st[ct][1]);
      pk[2] = f2bf(st[ct][2]);
      pk[3] = f2bf(st[ct][3]);
      *(short4v*)&p_lds[pb + ct * 16 + quad * 4] = pk;
    }
    __syncthreads();
    bf16x8 bp0 = *(const bf16x8*)&p_lds[pb + quad * 8];
    bf16x8 bp1 = *(const bf16x8*)&p_lds[pb + 32 + quad * 8];

    // O^T[d][i] += sum_j V^T[d][j] * P^T[j][i]
#pragma unroll
    for (int t = 0; t < 4; ++t) {
      const bf16* vrow = vb + (size_t)(t * 16 + l16) * S_LEN + j0;
      bf16x8 av0 = *(const bf16x8*)(vrow + quad * 8);
      bf16x8 av1 = *(const bf16x8*)(vrow + 32 + quad * 8);
      oT[t] = MFMA(av0, bp0, oT[t]);
      oT[t] = MFMA(av1, bp1, oT[t]);
    }
  }

  const float inv = 1.0f / l_i;
  const int b_ = bh >> 2, h = bh & 3;
  bf16* ob = attn + ((size_t)(b_ * S_LEN + q0 + wave * 16 + l16)) * D_MODEL + h * HD;
#pragma unroll
  for (int t = 0; t < 4; ++t) {
    short4v pk;
#pragma unroll
    for (int r = 0; r < 4; ++r) pk[r] = f2bf(oT[t][r] * inv);
    *(short4v*)(ob + t * 16 + quad * 4) = pk;
  }
}

// ---------------------------------------------------------------------------
// Kernel 3: out-projection (attn @ wo.T + bo) + LayerNorm, per 16 tokens.
// attn is bf16 (ws); wo/bo/gamma/beta fp32; output fp32 to d_out. Writing
// d_out here kills the qg/kg staging data, which is dead by this point.
// ---------------------------------------------------------------------------
__global__ __launch_bounds__(256) void out_ln(
    const bf16* __restrict__ attn, const float* __restrict__ wo,
    const float* __restrict__ bo_, const float* __restrict__ gamma,
    const float* __restrict__ beta, float* __restrict__ out) {
  const int tid = threadIdx.x;
  const int wave = tid >> 6;
  const int lane = tid & 63;
  const int quad = lane >> 4;
  const int l16  = lane & 15;
  const int t0 = blockIdx.x * 16;

  __shared__ float ybuf[16 * 256];
  __shared__ float mu_s[16], rs_s[16];

  f32x4 acc[4] = {};
  const int n0 = wave * 64;
  for (int kk = 0; kk < D_MODEL; kk += 32) {
    bf16x8 a = *(const bf16x8*)(attn + (size_t)(t0 + l16) * D_MODEL + kk + quad * 8);
#pragma unroll
    for (int nt = 0; nt < 4; ++nt) {
      bf16x8 b = cvt8(wo + (size_t)(n0 + nt * 16 + l16) * D_MODEL + kk + quad * 8);
      acc[nt] = MFMA(a, b, acc[nt]);
    }
  }
#pragma unroll
  for (int nt = 0; nt < 4; ++nt) {
    const int o = n0 + nt * 16 + l16;
    const float bias = bo_[o];
#pragma unroll
    for (int r = 0; r < 4; ++r) ybuf[(quad * 4 + r) * 256 + o] = acc[nt][r] + bias;
  }
  __syncthreads();

  // wave w reduces rows [4w, 4w+4)
#pragma unroll
  for (int rr = 0; rr < 4; ++rr) {
    const int row = wave * 4 + rr;
    float s1 = 0.f, s2 = 0.f;
#pragma unroll
    for (int c = 0; c < 4; ++c) {
      const float v = ybuf[row * 256 + c * 64 + lane];
      s1 += v;
      s2 += v * v;
    }
#pragma unroll
    for (int m = 32; m >= 1; m >>= 1) {
      s1 += __shfl_xor(s1, m);
      s2 += __shfl_xor(s2, m);
    }
    if (lane == 0) {
      const float mu = s1 * (1.f / 256.f);
      const float var = s2 * (1.f / 256.f) - mu * mu;
      mu_s[row] = mu;
      rs_s[row] = rsqrtf(var + 1e-5f);
    }
  }
  __syncthreads();

  const float g  = gamma[tid];
  const float be = beta[tid];
#pragma unroll 4
  for (int row = 0; row < 16; ++row) {
    const float v = ybuf[row * 256 + tid];
    const float o = (v - mu_s[row]) * rs_s[row] * g + be;
    out[(size_t)(t0 + row) * D_MODEL + tid] = o;
  }
}

// ---------------------------------------------------------------------------
extern "C" void kernel_launch(void* const* d_in, const int* in_sizes, int n_in,
                              void* d_out, int out_size, void* d_ws, size_t ws_size,
                              hipStream_t stream) {
  const float* q_in  = (const float*)d_in[0];
  const float* k_in  = (const float*)d_in[1];
  const float* v_in  = (const float*)d_in[2];
  const float* wq    = (const float*)d_in[3];
  const float* bq    = (const float*)d_in[4];
  const float* wk    = (const float*)d_in[5];
  const float* bk    = (const float*)d_in[6];
  const float* wv    = (const float*)d_in[7];
  const float* bv    = (const float*)d_in[8];
  const float* wo    = (const float*)d_in[9];
  const float* bo    = (const float*)d_in[10];
  const float* gamma = (const float*)d_in[11];
  const float* beta  = (const float*)d_in[12];
  float* out = (float*)d_out;

  // Mode-B-proven layout (validated in R3): qg/kg staged as bf16 inside the
  // fp32 d_out buffer (2 x SEG bf16 = 8 MB = out_size fp32 exactly); vt and
  // attn in ws (8 MB). out_ln overwrites d_out last, when qg/kg are dead.
  const size_t SEG = (size_t)NTOK * D_MODEL;  // 2,097,152 elements
  bf16* qg   = (bf16*)d_out;
  bf16* kg   = (bf16*)d_out + SEG;
  bf16* vt   = (bf16*)d_ws;
  bf16* attn = (bf16*)d_ws + SEG;

  qkv_proj<<<dim3(128, 4, 3), 256, 0, stream>>>(q_in, k_in, v_in, wq, bq, wk, bk, wv, bv,
                                                qg, kg, vt);
  attn_fwd<<<dim3(64, 8), 256, 0, stream>>>(qg, kg, vt, attn);
  out_ln<<<dim3(512), 256, 0, stream>>>(attn, wo, bo, gamma, beta, out);
}

// Round 9
// 392.076 us; speedup vs baseline: 1.0986x; 1.0086x over previous
//
#include <hip/hip_runtime.h>
#include <hip/hip_bf16.h>

using bf16 = __hip_bfloat16;
typedef __attribute__((ext_vector_type(8))) short bf16x8;   // 8 bf16 in 4 VGPRs (MFMA A/B frag)
typedef __attribute__((ext_vector_type(4))) short short4v;  // 4 bf16 packed store
typedef __attribute__((ext_vector_type(4))) float f32x4;    // MFMA C/D frag

#define MFMA(a, b, c) __builtin_amdgcn_mfma_f32_16x16x32_bf16((a), (b), (c), 0, 0, 0)

// Problem constants
#define S_LEN 4096
#define D_MODEL 256
#define NH 4
#define HD 64
#define NTOK 8192   // B*S
#define PROW 72     // P-tile LDS row stride in shorts (144 B): 16B-aligned,
                    // spreads accesses across all 32 banks (proven R8:
                    // conflicts 3.46e7 -> 3.1e6)

// DTYPE RESOLUTION (R3-R8 evidence): inputs and output are FP32, per the
// reference. Every bf16-cast variant (R4-R7) NaN'd on garbage Q/K/V; R8's
// fp32 pipeline passed. Do NOT cast d_in to bf16.

static __device__ __forceinline__ short f2bf(float f) {
  bf16 h = __float2bfloat16(f);
  return *reinterpret_cast<short*>(&h);
}

// 8 consecutive fp32 -> bf16x8 MFMA fragment (two float4 loads + inline cvt).
static __device__ __forceinline__ bf16x8 cvt8(const float* p) {
  const float4 a = ((const float4*)p)[0];
  const float4 b = ((const float4*)p)[1];
  bf16x8 r;
  r[0] = f2bf(a.x); r[1] = f2bf(a.y); r[2] = f2bf(a.z); r[3] = f2bf(a.w);
  r[4] = f2bf(b.x); r[5] = f2bf(b.y); r[6] = f2bf(b.z); r[7] = f2bf(b.w);
  return r;
}

// ---------------------------------------------------------------------------
// Kernel 1: QKV projections. fp32 inputs/weights, bf16 outputs (MFMA staging).
//   z=0: Q = (x@wq.T + bq) * 0.125  -> qg[b][h][s][hd]   (scale folded in)
//   z=1: K = (x@wk.T + bk)          -> kg[b][h][s][hd]
//   z=2: V = (x@wv.T + bv)          -> vt[b][h][hd][s]   (swapped MFMA roles)
// MFMA 16x16x32 layouts (HW-verified): A[m=lane&15][k=quad*8+j],
// B[k=quad*8+j][n=lane&15], C/D row=quad*4+reg col=lane&15.
// PROVEN in R8 — unchanged.
// ---------------------------------------------------------------------------
__global__ __launch_bounds__(256) void qkv_proj(
    const float* __restrict__ q_in, const float* __restrict__ k_in, const float* __restrict__ v_in,
    const float* __restrict__ wq, const float* __restrict__ bq_,
    const float* __restrict__ wk, const float* __restrict__ bk_,
    const float* __restrict__ wv, const float* __restrict__ bv_,
    bf16* __restrict__ qg, bf16* __restrict__ kg, bf16* __restrict__ vtg) {
  const int wave = threadIdx.x >> 6;
  const int lane = threadIdx.x & 63;
  const int quad = lane >> 4;
  const int l16  = lane & 15;
  const int z = blockIdx.z;

  const float* X  = (z == 0) ? q_in : (z == 1) ? k_in : v_in;
  const float* W  = (z == 0) ? wq   : (z == 1) ? wk   : wv;
  const float* Bp = (z == 0) ? bq_  : (z == 1) ? bk_  : bv_;

  f32x4 acc[4] = {};

  if (z < 2) {
    // M = tokens, N = output channels
    const int m0 = blockIdx.x * 64 + wave * 16;
    const int n0 = blockIdx.y * 64;
    for (int kk = 0; kk < D_MODEL; kk += 32) {
      bf16x8 a = cvt8(X + (size_t)(m0 + l16) * D_MODEL + kk + quad * 8);
#pragma unroll
      for (int nt = 0; nt < 4; ++nt) {
        bf16x8 b = cvt8(W + (size_t)(n0 + nt * 16 + l16) * D_MODEL + kk + quad * 8);
        acc[nt] = MFMA(a, b, acc[nt]);
      }
    }
    bf16* dst = (z == 0) ? qg : kg;
    const float scale = (z == 0) ? 0.125f : 1.0f;  // 1/sqrt(HD) folded into Q
#pragma unroll
    for (int nt = 0; nt < 4; ++nt) {
      const int o = n0 + nt * 16 + l16;
      const float bias = Bp[o];
      const int h = o >> 6, hd = o & 63;
#pragma unroll
      for (int r = 0; r < 4; ++r) {
        const int t = m0 + quad * 4 + r;
        const int b_ = t >> 12, s = t & 4095;
        const float v = (acc[nt][r] + bias) * scale;
        dst[((size_t)((b_ * NH + h) * S_LEN + s)) * HD + hd] = __float2bfloat16(v);
      }
    }
  } else {
    // V transposed: M = output channels, N = tokens
    const int o0 = blockIdx.y * 64 + wave * 16;
    const int t0 = blockIdx.x * 64;
    for (int kk = 0; kk < D_MODEL; kk += 32) {
      bf16x8 a = cvt8(W + (size_t)(o0 + l16) * D_MODEL + kk + quad * 8);
#pragma unroll
      for (int nt = 0; nt < 4; ++nt) {
        bf16x8 b = cvt8(X + (size_t)(t0 + nt * 16 + l16) * D_MODEL + kk + quad * 8);
        acc[nt] = MFMA(a, b, acc[nt]);
      }
    }
    const int h = blockIdx.y;  // o0 block aligned to head boundary (64)
#pragma unroll
    for (int r = 0; r < 4; ++r) {
      const int o = o0 + quad * 4 + r;
      const float bias = Bp[o];
      const int hd = o & 63;
#pragma unroll
      for (int nt = 0; nt < 4; ++nt) {
        const int t = t0 + nt * 16 + l16;
        const int b_ = t >> 12, s = t & 4095;
        vtg[((size_t)((b_ * NH + h) * HD + hd)) * S_LEN + s] = __float2bfloat16(acc[nt][r] + bias);
      }
    }
  }
}

// ---------------------------------------------------------------------------
// Kernel 2: flash attention, transposed-score formulation. All-bf16 internal.
//   R9 perf structure (revived from R4 — exonerated by the dtype finding):
//   (1) K/V fragments register-double-buffered one 64-key tile ahead (global
//       load latency overlaps previous tile's compute);
//   (2) NO per-iteration __syncthreads: the P LDS round-trip is wave-private,
//       same-wave DS ops are in-order; asm memory clobbers on both sides stop
//       compiler reordering (RAW and next-iteration WAR);
//   (3) PROW=72 padding (proven R8).
//   S^T = K·Q^T (softmax reduction on quad/reg axis, 2 shuffles for stats);
//   O^T = V^T·P^T accumulated in C-layout.
//   If this round NaNs: barrier-free wave-private LDS is falsified cleanly ->
//   restore __syncthreads ONLY (keep prefetch).
// ---------------------------------------------------------------------------
#define LOAD_KV(kf, vf, jbase)                                             \
  {                                                                        \
    const int jb_ = (jbase);                                               \
    _Pragma("unroll")                                                      \
    for (int ct = 0; ct < 4; ++ct) {                                       \
      const bf16* krow = kb + (size_t)(jb_ + ct * 16 + l16) * HD;          \
      kf[ct][0] = *(const bf16x8*)(krow + quad * 8);                       \
      kf[ct][1] = *(const bf16x8*)(krow + 32 + quad * 8);                  \
    }                                                                      \
    _Pragma("unroll")                                                      \
    for (int t = 0; t < 4; ++t) {                                          \
      const bf16* vrow = vb + (size_t)(t * 16 + l16) * S_LEN + jb_;        \
      vf[t][0] = *(const bf16x8*)(vrow + quad * 8);                        \
      vf[t][1] = *(const bf16x8*)(vrow + 32 + quad * 8);                   \
    }                                                                      \
  }

#define PROCESS(kf, vf)                                                    \
  {                                                                        \
    f32x4 st[4] = {};                                                      \
    _Pragma("unroll")                                                      \
    for (int ct = 0; ct < 4; ++ct) {                                       \
      st[ct] = MFMA(kf[ct][0], qf0, st[ct]);                               \
      st[ct] = MFMA(kf[ct][1], qf1, st[ct]);                               \
    }                                                                      \
    float mx = st[0][0];                                                   \
    _Pragma("unroll")                                                      \
    for (int ct = 0; ct < 4; ++ct)                                         \
      _Pragma("unroll")                                                    \
      for (int r = 0; r < 4; ++r) mx = fmaxf(mx, st[ct][r]);               \
    mx = fmaxf(mx, __shfl_xor(mx, 16));                                    \
    mx = fmaxf(mx, __shfl_xor(mx, 32));                                    \
    const float m_new = fmaxf(m_i, mx);                                    \
    const float alpha = __expf(m_i - m_new);                               \
    float rs = 0.f;                                                        \
    _Pragma("unroll")                                                      \
    for (int ct = 0; ct < 4; ++ct)                                         \
      _Pragma("unroll")                                                    \
      for (int r = 0; r < 4; ++r) {                                        \
        const float p = __expf(st[ct][r] - m_new);                         \
        st[ct][r] = p;                                                     \
        rs += p;                                                           \
      }                                                                    \
    rs += __shfl_xor(rs, 16);                                              \
    rs += __shfl_xor(rs, 32);                                              \
    l_i = l_i * alpha + rs;                                                \
    m_i = m_new;                                                           \
    _Pragma("unroll")                                                      \
    for (int t = 0; t < 4; ++t)                                            \
      _Pragma("unroll")                                                    \
      for (int r = 0; r < 4; ++r) oT[t][r] *= alpha;                       \
    asm volatile("" ::: "memory"); /* WAR: prior reads before new writes */ \
    _Pragma("unroll")                                                      \
    for (int ct = 0; ct < 4; ++ct) {                                       \
      short4v pk;                                                          \
      pk[0] = f2bf(st[ct][0]);                                             \
      pk[1] = f2bf(st[ct][1]);                                             \
      pk[2] = f2bf(st[ct][2]);                                             \
      pk[3] = f2bf(st[ct][3]);                                             \
      *(short4v*)&p_lds[pb + ct * 16 + quad * 4] = pk;                     \
    }                                                                      \
    asm volatile("" ::: "memory"); /* RAW: writes before reads */          \
    bf16x8 bp0 = *(const bf16x8*)&p_lds[pb + quad * 8];                    \
    bf16x8 bp1 = *(const bf16x8*)&p_lds[pb + 32 + quad * 8];               \
    _Pragma("unroll")                                                      \
    for (int t = 0; t < 4; ++t) {                                          \
      oT[t] = MFMA(vf[t][0], bp0, oT[t]);                                  \
      oT[t] = MFMA(vf[t][1], bp1, oT[t]);                                  \
    }                                                                      \
  }

__global__ __launch_bounds__(256) void attn_fwd(
    const bf16* qg, const bf16* kg, const bf16* vtg, bf16* attn) {
  const int wave = threadIdx.x >> 6;
  const int lane = threadIdx.x & 63;
  const int quad = lane >> 4;
  const int l16  = lane & 15;
  const int q0 = blockIdx.x * 64;
  const int bh = blockIdx.y;

  const bf16* qb = qg  + (size_t)bh * S_LEN * HD;
  const bf16* kb = kg  + (size_t)bh * S_LEN * HD;
  const bf16* vb = vtg + (size_t)bh * HD * S_LEN;

  __shared__ short p_lds[4 * 16 * PROW];  // per-wave 16(q) x 64(j) bf16, padded rows

  const int qrow = q0 + wave * 16 + l16;
  bf16x8 qf0 = *(const bf16x8*)(qb + (size_t)qrow * HD + quad * 8);
  bf16x8 qf1 = *(const bf16x8*)(qb + (size_t)qrow * HD + 32 + quad * 8);

  float m_i = -1.0e30f, l_i = 0.f;
  f32x4 oT[4] = {};
  const int pb = wave * (16 * PROW) + l16 * PROW;

  bf16x8 kA[4][2], vA[4][2], kB[4][2], vB[4][2];

  LOAD_KV(kA, vA, 0)
  for (int j0 = 0; j0 < S_LEN; j0 += 128) {
    LOAD_KV(kB, vB, j0 + 64)                      // j0+64 <= 4032, in bounds
    PROCESS(kA, vA)
    if (j0 + 128 < S_LEN) LOAD_KV(kA, vA, j0 + 128)
    PROCESS(kB, vB)
  }

  const float inv = 1.0f / l_i;
  const int b_ = bh >> 2, h = bh & 3;
  bf16* ob = attn + ((size_t)(b_ * S_LEN + q0 + wave * 16 + l16)) * D_MODEL + h * HD;
#pragma unroll
  for (int t = 0; t < 4; ++t) {
    short4v pk;
#pragma unroll
    for (int r = 0; r < 4; ++r) pk[r] = f2bf(oT[t][r] * inv);
    *(short4v*)(ob + t * 16 + quad * 4) = pk;
  }
}

// ---------------------------------------------------------------------------
// Kernel 3: out-projection (attn @ wo.T + bo) + LayerNorm, per 16 tokens.
// attn is bf16 (ws); wo/bo/gamma/beta fp32; output fp32 to d_out. Writing
// d_out here kills the qg/kg staging data, which is dead by this point.
// PROVEN in R8 — unchanged.
// ---------------------------------------------------------------------------
__global__ __launch_bounds__(256) void out_ln(
    const bf16* __restrict__ attn, const float* __restrict__ wo,
    const float* __restrict__ bo_, const float* __restrict__ gamma,
    const float* __restrict__ beta, float* __restrict__ out) {
  const int tid = threadIdx.x;
  const int wave = tid >> 6;
  const int lane = tid & 63;
  const int quad = lane >> 4;
  const int l16  = lane & 15;
  const int t0 = blockIdx.x * 16;

  __shared__ float ybuf[16 * 256];
  __shared__ float mu_s[16], rs_s[16];

  f32x4 acc[4] = {};
  const int n0 = wave * 64;
  for (int kk = 0; kk < D_MODEL; kk += 32) {
    bf16x8 a = *(const bf16x8*)(attn + (size_t)(t0 + l16) * D_MODEL + kk + quad * 8);
#pragma unroll
    for (int nt = 0; nt < 4; ++nt) {
      bf16x8 b = cvt8(wo + (size_t)(n0 + nt * 16 + l16) * D_MODEL + kk + quad * 8);
      acc[nt] = MFMA(a, b, acc[nt]);
    }
  }
#pragma unroll
  for (int nt = 0; nt < 4; ++nt) {
    const int o = n0 + nt * 16 + l16;
    const float bias = bo_[o];
#pragma unroll
    for (int r = 0; r < 4; ++r) ybuf[(quad * 4 + r) * 256 + o] = acc[nt][r] + bias;
  }
  __syncthreads();

  // wave w reduces rows [4w, 4w+4)
#pragma unroll
  for (int rr = 0; rr < 4; ++rr) {
    const int row = wave * 4 + rr;
    float s1 = 0.f, s2 = 0.f;
#pragma unroll
    for (int c = 0; c < 4; ++c) {
      const float v = ybuf[row * 256 + c * 64 + lane];
      s1 += v;
      s2 += v * v;
    }
#pragma unroll
    for (int m = 32; m >= 1; m >>= 1) {
      s1 += __shfl_xor(s1, m);
      s2 += __shfl_xor(s2, m);
    }
    if (lane == 0) {
      const float mu = s1 * (1.f / 256.f);
      const float var = s2 * (1.f / 256.f) - mu * mu;
      mu_s[row] = mu;
      rs_s[row] = rsqrtf(var + 1e-5f);
    }
  }
  __syncthreads();

  const float g  = gamma[tid];
  const float be = beta[tid];
#pragma unroll 4
  for (int row = 0; row < 16; ++row) {
    const float v = ybuf[row * 256 + tid];
    const float o = (v - mu_s[row]) * rs_s[row] * g + be;
    out[(size_t)(t0 + row) * D_MODEL + tid] = o;
  }
}

// ---------------------------------------------------------------------------
extern "C" void kernel_launch(void* const* d_in, const int* in_sizes, int n_in,
                              void* d_out, int out_size, void* d_ws, size_t ws_size,
                              hipStream_t stream) {
  const float* q_in  = (const float*)d_in[0];
  const float* k_in  = (const float*)d_in[1];
  const float* v_in  = (const float*)d_in[2];
  const float* wq    = (const float*)d_in[3];
  const float* bq    = (const float*)d_in[4];
  const float* wk    = (const float*)d_in[5];
  const float* bk    = (const float*)d_in[6];
  const float* wv    = (const float*)d_in[7];
  const float* bv    = (const float*)d_in[8];
  const float* wo    = (const float*)d_in[9];
  const float* bo    = (const float*)d_in[10];
  const float* gamma = (const float*)d_in[11];
  const float* beta  = (const float*)d_in[12];
  float* out = (float*)d_out;

  // Mode-B-proven layout (R3/R8): qg/kg staged as bf16 inside the fp32 d_out
  // buffer (2 x SEG bf16 = 8 MB = out_size fp32 exactly); vt and attn in ws
  // (8 MB). out_ln overwrites d_out last, when qg/kg are dead.
  const size_t SEG = (size_t)NTOK * D_MODEL;  // 2,097,152 elements
  bf16* qg   = (bf16*)d_out;
  bf16* kg   = (bf16*)d_out + SEG;
  bf16* vt   = (bf16*)d_ws;
  bf16* attn = (bf16*)d_ws + SEG;

  qkv_proj<<<dim3(128, 4, 3), 256, 0, stream>>>(q_in, k_in, v_in, wq, bq, wk, bk, wv, bv,
                                                qg, kg, vt);
  attn_fwd<<<dim3(64, 8), 256, 0, stream>>>(qg, kg, vt, attn);
  out_ln<<<dim3(512), 256, 0, stream>>>(attn, wo, bo, gamma, beta, out);
}